// Round 1
// baseline (303.787 us; speedup 1.0000x reference)
//
#include <hip/hip_runtime.h>
#include <hip/hip_bf16.h>

#define BB 4
#define NN 4096
#define DD 128
#define HH 4

typedef __attribute__((ext_vector_type(8))) short bf16x8;
typedef __attribute__((ext_vector_type(4))) float f32x4;

__device__ __forceinline__ unsigned short f2bf(float f) {
    unsigned int u = __float_as_uint(f);
    unsigned int r = (u + 0x7FFFu + ((u >> 16) & 1u)) >> 16;
    return (unsigned short)r;
}
__device__ __forceinline__ float bf2f(unsigned short s) {
    return __uint_as_float(((unsigned int)s) << 16);
}

// ---------------- kernel 1: cast x -> bf16, x2 row sums (from bf16 values) ----
__global__ __launch_bounds__(256) void prep_kernel(const float* __restrict__ x,
                                                   short* __restrict__ xb,
                                                   float* __restrict__ x2) {
    int lane = threadIdx.x & 63, wave = threadIdx.x >> 6;
    size_t row = (size_t)blockIdx.x * 4 + wave;   // < B*N
    const float* xr = x + row * DD;
    float2 v = *(const float2*)(xr + lane * 2);
    unsigned short b0 = f2bf(v.x), b1 = f2bf(v.y);
    ushort2 st; st.x = b0; st.y = b1;
    *(ushort2*)((unsigned short*)xb + row * DD + lane * 2) = st;
    float f0 = bf2f(b0), f1 = bf2f(b1);
    float s = f0 * f0 + f1 * f1;
    #pragma unroll
    for (int off = 32; off; off >>= 1) s += __shfl_xor(s, off);
    if (lane == 0) x2[row] = s;
}

// ---------------- kernel 1b: Wt[k][d] = W[d][k] ------------------------------
__global__ __launch_bounds__(256) void wt_kernel(const float* __restrict__ W,
                                                 float* __restrict__ Wt) {
    int idx = blockIdx.x * 256 + threadIdx.x;  // 16384
    int d = idx >> 7, k = idx & 127;
    Wt[k * DD + d] = W[d * DD + k];
}

// ---------------- kernel 2: fused adjacency + diffusion ----------------------
// grid = B * (N/64) = 256 blocks, 256 threads (4 waves). Each block: 64 n-rows.
#define QP 136
#define KP 136
#define TP 72

__global__ __launch_bounds__(256) void attn_kernel(const short* __restrict__ xb,
                                                   const float* __restrict__ x2,
                                                   const float* __restrict__ log_sigmas,
                                                   float* __restrict__ out) {
    __shared__ short Qs[64 * QP];
    __shared__ short Ks[64 * KP];
    __shared__ short Kt[128 * TP];
    __shared__ short Ws[64 * TP];

    int tid = threadIdx.x, lane = tid & 63, wave = tid >> 6;
    int b = blockIdx.x >> 6;
    int n0 = (blockIdx.x & 63) * 64;

    float invd[HH];
    #pragma unroll
    for (int h = 0; h < HH; ++h) {
        float s = __expf(log_sigmas[h]);
        invd[h] = 1.0f / (2.0f * s * s + 1e-6f);
    }
    bool same = (invd[0] == invd[1]) && (invd[1] == invd[2]) && (invd[2] == invd[3]);

    const short* xbb = xb + (size_t)b * NN * DD;
    const float* x2b = x2 + (size_t)b * NN;

    // stage Q (64 x 128 bf16)
    for (int c = tid; c < 64 * 16; c += 256) {
        int row = c >> 4, c8 = (c & 15) << 3;
        *(uint4*)(&Qs[row * QP + c8]) = *(const uint4*)(xbb + ((size_t)(n0 + row)) * DD + c8);
    }

    int fr = lane & 15;            // fragment row/col
    int fk = (lane >> 4) << 3;     // k offset within 32-slice
    int r0 = wave * 16 + ((lane >> 4) << 2);  // C-layout row base (local)

    float x2n[4];
    #pragma unroll
    for (int r = 0; r < 4; ++r) x2n[r] = x2b[n0 + r0 + r];

    f32x4 O[8];
    #pragma unroll
    for (int i = 0; i < 8; ++i) O[i] = (f32x4){0.f, 0.f, 0.f, 0.f};

    for (int mt = 0; mt < NN / 64; ++mt) {
        int m0 = mt * 64;
        __syncthreads();  // protect Ks/Kt (prev iter reads done)
        // stage K row-major + transposed
        for (int c = tid; c < 64 * 16; c += 256) {
            int row = c >> 4, c8 = (c & 15) << 3;
            uint4 v = *(const uint4*)(xbb + ((size_t)(m0 + row)) * DD + c8);
            *(uint4*)(&Ks[row * KP + c8]) = v;
            const short* p = (const short*)&v;
            #pragma unroll
            for (int i = 0; i < 8; ++i) Kt[(c8 + i) * TP + row] = p[i];
        }
        __syncthreads();

        // S = Q . K^T  (per wave: 16 x 64)
        f32x4 S[4];
        #pragma unroll
        for (int ct = 0; ct < 4; ++ct) S[ct] = (f32x4){0.f, 0.f, 0.f, 0.f};
        #pragma unroll
        for (int ks = 0; ks < 4; ++ks) {
            bf16x8 a = *(const bf16x8*)(&Qs[(wave * 16 + fr) * QP + ks * 32 + fk]);
            #pragma unroll
            for (int ct = 0; ct < 4; ++ct) {
                bf16x8 bb = *(const bf16x8*)(&Ks[(ct * 16 + fr) * KP + ks * 32 + fk]);
                S[ct] = __builtin_amdgcn_mfma_f32_16x16x32_bf16(a, bb, S[ct], 0, 0, 0);
            }
        }

        // weights -> bf16 -> Ws (wave-private rows)
        #pragma unroll
        for (int ct = 0; ct < 4; ++ct) {
            float x2m = x2b[m0 + ct * 16 + fr];
            #pragma unroll
            for (int r = 0; r < 4; ++r) {
                float dsq = fmaxf(x2n[r] + x2m - 2.0f * S[ct][r], 0.0f);
                float w;
                if (same) {
                    w = __expf(-dsq * invd[0]);
                } else {
                    w = 0.25f * (__expf(-dsq * invd[0]) + __expf(-dsq * invd[1]) +
                                 __expf(-dsq * invd[2]) + __expf(-dsq * invd[3]));
                }
                Ws[(r0 + r) * TP + ct * 16 + fr] = (short)f2bf(w);
            }
        }
        __syncthreads();  // conservative (Ws is wave-private; keep safe this round)

        // O += W . V   (per wave: 16 x 128)
        #pragma unroll
        for (int ks = 0; ks < 2; ++ks) {
            bf16x8 a = *(const bf16x8*)(&Ws[(wave * 16 + fr) * TP + ks * 32 + fk]);
            #pragma unroll
            for (int ct = 0; ct < 8; ++ct) {
                bf16x8 bb = *(const bf16x8*)(&Kt[(ct * 16 + fr) * TP + ks * 32 + fk]);
                O[ct] = __builtin_amdgcn_mfma_f32_16x16x32_bf16(a, bb, O[ct], 0, 0, 0);
            }
        }
    }

    float* Op = out + ((size_t)b * NN + n0) * DD;
    #pragma unroll
    for (int ct = 0; ct < 8; ++ct)
        #pragma unroll
        for (int r = 0; r < 4; ++r)
            Op[(size_t)(r0 + r) * DD + ct * 16 + fr] = O[ct][r];
}

// ---------------- kernel 3: proj + ELU + residual + LayerNorm (in-place) -----
// grid = 256 blocks x 256 threads; block handles 64 rows, 1 wave per row.
__global__ __launch_bounds__(256) void epi_kernel(const float* __restrict__ x,
                                                  const float* __restrict__ Wt,
                                                  const float* __restrict__ pb,
                                                  const float* __restrict__ gamma,
                                                  const float* __restrict__ beta,
                                                  float* io) {
    __shared__ float WtL[128 * 128];
    __shared__ float orow[4][128];
    int tid = threadIdx.x, lane = tid & 63, wave = tid >> 6;

    for (int i = tid; i < 4096; i += 256)
        ((float4*)WtL)[i] = ((const float4*)Wt)[i];

    float b0 = pb[lane], b1 = pb[lane + 64];
    float g0 = gamma[lane], g1 = gamma[lane + 64];
    float be0 = beta[lane], be1 = beta[lane + 64];
    __syncthreads();

    for (int it = 0; it < 16; ++it) {
        size_t row = (size_t)blockIdx.x * 64 + it * 4 + wave;
        float* orp = io + row * DD;
        orow[wave][lane] = orp[lane];
        orow[wave][lane + 64] = orp[lane + 64];
        __syncthreads();  // conservative; orow is wave-private

        float a0 = b0, a1 = b1;
        #pragma unroll 16
        for (int k = 0; k < 128; ++k) {
            float o = orow[wave][k];
            a0 = fmaf(o, WtL[k * 128 + lane], a0);
            a1 = fmaf(o, WtL[k * 128 + 64 + lane], a1);
        }
        float xv0 = x[row * DD + lane], xv1 = x[row * DD + 64 + lane];
        float y0 = (a0 > 0.f ? a0 : expm1f(a0)) + xv0;
        float y1 = (a1 > 0.f ? a1 : expm1f(a1)) + xv1;

        float s = y0 + y1;
        #pragma unroll
        for (int off = 32; off; off >>= 1) s += __shfl_xor(s, off);
        float mu = s * 0.0078125f;
        float d0 = y0 - mu, d1 = y1 - mu;
        float v = d0 * d0 + d1 * d1;
        #pragma unroll
        for (int off = 32; off; off >>= 1) v += __shfl_xor(v, off);
        float inv = rsqrtf(v * 0.0078125f + 1e-5f);

        orp[lane]      = d0 * inv * g0 + be0;
        orp[lane + 64] = d1 * inv * g1 + be1;
        __syncthreads();
    }
}

extern "C" void kernel_launch(void* const* d_in, const int* in_sizes, int n_in,
                              void* d_out, int out_size, void* d_ws, size_t ws_size,
                              hipStream_t stream) {
    const float* x  = (const float*)d_in[0];
    const float* ls = (const float*)d_in[1];
    const float* pw = (const float*)d_in[2];
    const float* pb = (const float*)d_in[3];
    const float* g  = (const float*)d_in[4];
    const float* be = (const float*)d_in[5];
    float* out = (float*)d_out;

    char* ws = (char*)d_ws;
    short* xb = (short*)ws;                                   // B*N*D bf16 = 4 MB
    float* x2 = (float*)(ws + (size_t)4 * 1024 * 1024);       // B*N f32 = 64 KB
    float* Wt = (float*)(ws + (size_t)4 * 1024 * 1024 + 64 * 1024);  // 64 KB

    prep_kernel<<<dim3(BB * NN / 4), dim3(256), 0, stream>>>(x, xb, x2);
    wt_kernel<<<dim3(64), dim3(256), 0, stream>>>(pw, Wt);
    attn_kernel<<<dim3(BB * NN / 64), dim3(256), 0, stream>>>(xb, x2, ls, out);
    epi_kernel<<<dim3(256), dim3(256), 0, stream>>>(x, Wt, pb, g, be, out);
}

// Round 3
// 119.705 us; speedup vs baseline: 2.5378x; 2.5378x over previous
//
#include <hip/hip_runtime.h>
#include <hip/hip_bf16.h>

#define BB 4
#define NN 4096
#define DD 128

typedef __attribute__((ext_vector_type(8))) short bf16x8;
typedef __attribute__((ext_vector_type(4))) float f32x4;

#define GAS __attribute__((address_space(1)))
#define LAS __attribute__((address_space(3)))

__device__ __forceinline__ unsigned short f2bf(float f) {
    unsigned int u = __float_as_uint(f);
    return (unsigned short)((u + 0x7FFFu + ((u >> 16) & 1u)) >> 16);
}
__device__ __forceinline__ float bf2f(unsigned short s) {
    return __uint_as_float(((unsigned int)s) << 16);
}
__device__ __forceinline__ void gload16(const void* g, void* l) {
    __builtin_amdgcn_global_load_lds((const GAS unsigned int*)g,
                                     (LAS unsigned int*)l, 16, 0, 0);
}

// ---------- kernel 1: x -> bf16 (xb row-major, xbT [b][d][n]), x2 row sums ----
__global__ __launch_bounds__(256) void prep_kernel(const float* __restrict__ x,
        short* __restrict__ xb, short* __restrict__ xbT, float* __restrict__ x2) {
    __shared__ short Ls[64 * 136];
    int tid = threadIdx.x;
    int r = tid >> 2, cq = tid & 3;
    size_t rowg = (size_t)blockIdx.x * 64 + r;
    const float* xp = x + rowg * DD + cq * 32;
    short tmp[32];
    float s = 0.f;
    #pragma unroll
    for (int i = 0; i < 8; ++i) {
        float4 v = ((const float4*)xp)[i];
        unsigned short b0 = f2bf(v.x), b1 = f2bf(v.y), b2 = f2bf(v.z), b3 = f2bf(v.w);
        tmp[i*4+0] = (short)b0; tmp[i*4+1] = (short)b1;
        tmp[i*4+2] = (short)b2; tmp[i*4+3] = (short)b3;
        float f0 = bf2f(b0), f1 = bf2f(b1), f2 = bf2f(b2), f3 = bf2f(b3);
        s += f0*f0 + f1*f1 + f2*f2 + f3*f3;
    }
    #pragma unroll
    for (int i = 0; i < 4; ++i) {
        uint4 v = ((uint4*)tmp)[i];
        *(uint4*)(xb + rowg * DD + cq * 32 + i * 8) = v;
        *(uint4*)(&Ls[r * 136 + cq * 32 + i * 8]) = v;
    }
    s += __shfl_xor(s, 1); s += __shfl_xor(s, 2);
    if ((tid & 3) == 0) x2[rowg] = s;
    __syncthreads();
    // transposed write: thread -> (d, n-half)
    int d = (tid & 63) + ((tid >> 7) << 6);
    int nh = (tid >> 6) & 1;
    short arr[32];
    #pragma unroll
    for (int i = 0; i < 32; ++i) arr[i] = Ls[(nh * 32 + i) * 136 + d];
    int blk = blockIdx.x;
    size_t dst = ((size_t)(blk >> 6) * DD + d) * NN + (size_t)(blk & 63) * 64 + nh * 32;
    #pragma unroll
    for (int i = 0; i < 4; ++i)
        *(uint4*)(xbT + dst + i * 8) = ((uint4*)arr)[i];
}

// ---------- kernel 1b: proj_w f32 -> bf16 (row-major, no transpose) ----------
__global__ __launch_bounds__(256) void wt_kernel(const float* __restrict__ W,
                                                 short* __restrict__ Wb) {
    int i = (blockIdx.x * 256 + threadIdx.x) * 4;
    float4 v = *(const float4*)(W + i);
    ushort4 o; o.x = f2bf(v.x); o.y = f2bf(v.y); o.z = f2bf(v.z); o.w = f2bf(v.w);
    *(ushort4*)((unsigned short*)Wb + i) = o;
}

// ---------- kernel 2: fused adjacency + diffusion + projection ---------------
// grid = B*N/64 = 256 blocks, 512 threads (8 waves).
// wave w: row-group rg=w&3 (16 n-rows), half mh=w>>2 (m-half for QK^T/Ws,
// d-half for PV output, j-half for proj).
__global__ __launch_bounds__(512, 2) void attn_kernel(
        const short* __restrict__ xb, const short* __restrict__ xbT,
        const float* __restrict__ x2, const short* __restrict__ Wb,
        const float* __restrict__ log_sigmas, const float* __restrict__ pb,
        float* __restrict__ out) {
    __shared__ char smem[74752] __attribute__((aligned(128)));
    char* Kbuf = smem;            // 2 x 16384: [64 rows][256B], XOR-swizzled
    char* Vbuf = smem + 32768;    // 2 x 16384: [128 d][128B],  XOR-swizzled
    char* Wsb  = smem + 65536;    // [64 rows][144B]

    int tid = threadIdx.x, lane = tid & 63, w = tid >> 6;
    int fr = lane & 15, gl = lane >> 4;
    int rg = w & 3, mh = w >> 2;
    int wg = rg * 16;
    int b = blockIdx.x >> 6;
    int n0 = (blockIdx.x & 63) * 64;

    const char* xb_b  = (const char*)(xb  + (size_t)b * NN * DD);
    const char* xbT_b = (const char*)(xbT + (size_t)b * NN * DD);
    const float* x2b = x2 + (size_t)b * NN;

    float invd[4];
    #pragma unroll
    for (int h = 0; h < 4; ++h) {
        float sg = __expf(log_sigmas[h]);
        invd[h] = 1.0f / (2.0f * sg * sg + 1e-6f);
    }
    bool same = (invd[0] == invd[1]) && (invd[1] == invd[2]) && (invd[2] == invd[3]);
    float c0 = -invd[0];

    // Q fragments in registers (16 rows of this wave's row-group)
    bf16x8 qf[4];
    const char* qrow = xb_b + ((size_t)(n0 + wg + fr)) * 256;
    #pragma unroll
    for (int ks = 0; ks < 4; ++ks)
        qf[ks] = *(const bf16x8*)(qrow + ks * 64 + gl * 16);

    float x2n[4];
    #pragma unroll
    for (int r = 0; r < 4; ++r) x2n[r] = x2b[n0 + wg + gl * 4 + r];

    f32x4 O[4];
    #pragma unroll
    for (int i = 0; i < 4; ++i) O[i] = (f32x4){0.f, 0.f, 0.f, 0.f};

    auto stage = [&](int buf, int m1) {
        #pragma unroll
        for (int ii = 0; ii < 2; ++ii) {
            int I = w * 2 + ii;                    // K instr: 4 rows each
            int row = I * 4 + gl;
            int g = (lane & 15) ^ (row & 7);
            const char* src = xb_b + ((size_t)(m1 + row)) * 256 + g * 16;
            gload16(src, Kbuf + buf * 16384 + I * 1024);
        }
        #pragma unroll
        for (int ii = 0; ii < 2; ++ii) {
            int I = w * 2 + ii;                    // V instr: 8 d-rows each
            int d = I * 8 + (lane >> 3);
            int g = (lane & 7) ^ (d & 7);
            const char* src = xbT_b + (size_t)d * (NN * 2) + (size_t)m1 * 2 + g * 16;
            gload16(src, Vbuf + buf * 16384 + I * 1024);
        }
    };

    stage(0, 0);
    asm volatile("s_waitcnt vmcnt(0)" ::: "memory");
    __builtin_amdgcn_s_barrier();
    __builtin_amdgcn_sched_barrier(0);

    int cur = 0;
    for (int t = 0; t < NN / 64; ++t) {
        int m0 = t * 64;
        if (t < NN / 64 - 1) stage(cur ^ 1, m0 + 64);

        const char* Kc = Kbuf + cur * 16384;
        const char* Vc = Vbuf + cur * 16384;

        // S = Q . K^T  (per wave: 16 rows x 32 m-cols of this half)
        f32x4 S[2];
        #pragma unroll
        for (int c2 = 0; c2 < 2; ++c2) {
            S[c2] = (f32x4){0.f, 0.f, 0.f, 0.f};
            int rowk = mh * 32 + c2 * 16 + fr;
            const char* kr = Kc + rowk * 256;
            int sw = (rowk & 7) * 16;
            #pragma unroll
            for (int ks = 0; ks < 4; ++ks) {
                bf16x8 kf = *(const bf16x8*)(kr + (((ks * 4 + gl) * 16) ^ sw));
                S[c2] = __builtin_amdgcn_mfma_f32_16x16x32_bf16(qf[ks], kf, S[c2], 0, 0, 0);
            }
        }
        // weights -> bf16 -> Ws
        #pragma unroll
        for (int c2 = 0; c2 < 2; ++c2) {
            float x2m = x2b[m0 + mh * 32 + c2 * 16 + fr];
            #pragma unroll
            for (int r = 0; r < 4; ++r) {
                float dsq = fmaxf(x2n[r] + x2m - 2.0f * S[c2][r], 0.0f);
                float wv;
                if (same) wv = __expf(dsq * c0);
                else wv = 0.25f * (__expf(-dsq * invd[0]) + __expf(-dsq * invd[1]) +
                                   __expf(-dsq * invd[2]) + __expf(-dsq * invd[3]));
                ((short*)Wsb)[(wg + gl * 4 + r) * 72 + mh * 32 + c2 * 16 + fr] =
                    (short)f2bf(wv);
            }
        }
        // Ws visible to all waves; prefetch vmem stays in flight (T4)
        asm volatile("s_waitcnt lgkmcnt(0)" ::: "memory");
        __builtin_amdgcn_s_barrier();
        __builtin_amdgcn_sched_barrier(0);

        // O += W . V  (per wave: 16 rows x 64 d of this half)
        #pragma unroll
        for (int ks2 = 0; ks2 < 2; ++ks2) {
            bf16x8 af = *(const bf16x8*)(Wsb + (wg + fr) * 144 + ks2 * 64 + gl * 16);
            #pragma unroll
            for (int ct = 0; ct < 4; ++ct) {
                int d = mh * 64 + ct * 16 + fr;
                bf16x8 vf = *(const bf16x8*)(Vc + d * 128 +
                                (((ks2 * 4 + gl) * 16) ^ ((d & 7) * 16)));
                O[ct] = __builtin_amdgcn_mfma_f32_16x16x32_bf16(af, vf, O[ct], 0, 0, 0);
            }
        }
        __syncthreads();   // full drain: staged buffer ready, all PV reads done
        cur ^= 1;
    }

    // -------- epilogue: projection via MFMA (reuse staging LDS) --------
    short* Os  = (short*)smem;              // [64][136 shorts]
    short* Wbs = (short*)(smem + 17408);    // [128][136 shorts]
    #pragma unroll
    for (int ct = 0; ct < 4; ++ct)
        #pragma unroll
        for (int r = 0; r < 4; ++r)
            Os[(wg + gl * 4 + r) * 136 + mh * 64 + ct * 16 + fr] = (short)f2bf(O[ct][r]);
    {
        int j = tid >> 2, cq = tid & 3;
        const uint4* src = (const uint4*)(Wb + j * 128 + cq * 32);
        uint4* dst = (uint4*)(Wbs + j * 136 + cq * 32);
        dst[0] = src[0]; dst[1] = src[1]; dst[2] = src[2]; dst[3] = src[3];
    }
    __syncthreads();

    #pragma unroll
    for (int ct = 0; ct < 4; ++ct) {
        f32x4 P = (f32x4){0.f, 0.f, 0.f, 0.f};
        int j = mh * 64 + ct * 16 + fr;
        #pragma unroll
        for (int ks = 0; ks < 4; ++ks) {
            bf16x8 af = *(const bf16x8*)((const char*)Os + (wg + fr) * 272 + ks * 64 + gl * 16);
            bf16x8 bf = *(const bf16x8*)((const char*)Wbs + (size_t)j * 272 + ks * 64 + gl * 16);
            P = __builtin_amdgcn_mfma_f32_16x16x32_bf16(af, bf, P, 0, 0, 0);
        }
        float bias = pb[j];
        #pragma unroll
        for (int r = 0; r < 4; ++r)
            out[((size_t)b * NN + n0 + wg + gl * 4 + r) * DD + j] = P[r] + bias;
    }
}

// ---------- kernel 3: ELU + residual + LayerNorm (in-place, elementwise) -----
__global__ __launch_bounds__(256) void epi_kernel(const float* __restrict__ x,
        const float* __restrict__ gamma, const float* __restrict__ beta,
        float* io) {
    int lane = threadIdx.x & 63, wv = threadIdx.x >> 6;
    float g0 = gamma[lane * 2], g1 = gamma[lane * 2 + 1];
    float b0 = beta[lane * 2], b1 = beta[lane * 2 + 1];
    #pragma unroll
    for (int it = 0; it < 2; ++it) {
        size_t row = (size_t)blockIdx.x * 8 + it * 4 + wv;
        float2 o = *(const float2*)(io + row * DD + lane * 2);
        float2 xv = *(const float2*)(x + row * DD + lane * 2);
        float y0 = (o.x > 0.f ? o.x : __expf(o.x) - 1.f) + xv.x;
        float y1 = (o.y > 0.f ? o.y : __expf(o.y) - 1.f) + xv.y;
        float s = y0 + y1;
        #pragma unroll
        for (int off = 32; off; off >>= 1) s += __shfl_xor(s, off);
        float mu = s * 0.0078125f;
        float d0 = y0 - mu, d1 = y1 - mu;
        float v = d0 * d0 + d1 * d1;
        #pragma unroll
        for (int off = 32; off; off >>= 1) v += __shfl_xor(v, off);
        float inv = rsqrtf(v * 0.0078125f + 1e-5f);
        float2 rr; rr.x = d0 * inv * g0 + b0; rr.y = d1 * inv * g1 + b1;
        *(float2*)(io + row * DD + lane * 2) = rr;
    }
}

extern "C" void kernel_launch(void* const* d_in, const int* in_sizes, int n_in,
                              void* d_out, int out_size, void* d_ws, size_t ws_size,
                              hipStream_t stream) {
    const float* x  = (const float*)d_in[0];
    const float* ls = (const float*)d_in[1];
    const float* pw = (const float*)d_in[2];
    const float* pb = (const float*)d_in[3];
    const float* g  = (const float*)d_in[4];
    const float* be = (const float*)d_in[5];
    float* out = (float*)d_out;

    char* ws = (char*)d_ws;
    short* xb  = (short*)ws;                                  // 4 MB
    short* xbT = (short*)(ws + (size_t)4 * 1024 * 1024);      // 4 MB
    float* x2  = (float*)(ws + (size_t)8 * 1024 * 1024);      // 64 KB
    short* Wb  = (short*)(ws + (size_t)8 * 1024 * 1024 + 65536);  // 32 KB

    prep_kernel<<<dim3(BB * NN / 64), dim3(256), 0, stream>>>(x, xb, xbT, x2);
    wt_kernel<<<dim3(16), dim3(256), 0, stream>>>(pw, Wb);
    attn_kernel<<<dim3(BB * NN / 64), dim3(512), 0, stream>>>(xb, xbT, x2, Wb, ls, pb, out);
    epi_kernel<<<dim3(BB * NN / 8), dim3(256), 0, stream>>>(x, g, be, out);
}

// Round 4
// 93.486 us; speedup vs baseline: 3.2495x; 1.2805x over previous
//
#include <hip/hip_runtime.h>
#include <hip/hip_bf16.h>

#define BB 4
#define NN 4096
#define DD 128

typedef __attribute__((ext_vector_type(8))) short bf16x8;
typedef __attribute__((ext_vector_type(4))) float f32x4;
typedef __attribute__((ext_vector_type(16))) float f32x16;

#define GAS __attribute__((address_space(1)))
#define LAS __attribute__((address_space(3)))

__device__ __forceinline__ unsigned short f2bf(float f) {
    unsigned int u = __float_as_uint(f);
    return (unsigned short)((u + 0x7FFFu + ((u >> 16) & 1u)) >> 16);
}
__device__ __forceinline__ float bf2f(unsigned short s) {
    return __uint_as_float(((unsigned int)s) << 16);
}
__device__ __forceinline__ void gload16(const void* g, void* l) {
    __builtin_amdgcn_global_load_lds((const GAS unsigned int*)g,
                                     (LAS unsigned int*)l, 16, 0, 0);
}

// ---------- kernel 1: x -> bf16 (xb row-major, xbT [b][d][n]), x2 row sums ----
__global__ __launch_bounds__(256) void prep_kernel(const float* __restrict__ x,
        short* __restrict__ xb, short* __restrict__ xbT, float* __restrict__ x2) {
    __shared__ short Ls[64 * 136];
    int tid = threadIdx.x;
    int r = tid >> 2, cq = tid & 3;
    size_t rowg = (size_t)blockIdx.x * 64 + r;
    const float* xp = x + rowg * DD + cq * 32;
    short tmp[32];
    float s = 0.f;
    #pragma unroll
    for (int i = 0; i < 8; ++i) {
        float4 v = ((const float4*)xp)[i];
        unsigned short b0 = f2bf(v.x), b1 = f2bf(v.y), b2 = f2bf(v.z), b3 = f2bf(v.w);
        tmp[i*4+0] = (short)b0; tmp[i*4+1] = (short)b1;
        tmp[i*4+2] = (short)b2; tmp[i*4+3] = (short)b3;
        float f0 = bf2f(b0), f1 = bf2f(b1), f2 = bf2f(b2), f3 = bf2f(b3);
        s += f0*f0 + f1*f1 + f2*f2 + f3*f3;
    }
    #pragma unroll
    for (int i = 0; i < 4; ++i) {
        uint4 v = ((uint4*)tmp)[i];
        *(uint4*)(xb + rowg * DD + cq * 32 + i * 8) = v;
        *(uint4*)(&Ls[r * 136 + cq * 32 + i * 8]) = v;
    }
    s += __shfl_xor(s, 1); s += __shfl_xor(s, 2);
    if ((tid & 3) == 0) x2[rowg] = s;
    __syncthreads();
    int d = (tid & 63) + ((tid >> 7) << 6);
    int nh = (tid >> 6) & 1;
    short arr[32];
    #pragma unroll
    for (int i = 0; i < 32; ++i) arr[i] = Ls[(nh * 32 + i) * 136 + d];
    int blk = blockIdx.x;
    size_t dst = ((size_t)(blk >> 6) * DD + d) * NN + (size_t)(blk & 63) * 64 + nh * 32;
    #pragma unroll
    for (int i = 0; i < 4; ++i)
        *(uint4*)(xbT + dst + i * 8) = ((uint4*)arr)[i];
}

// ---------- kernel 1b: proj_w f32 -> bf16 (row-major) ------------------------
__global__ __launch_bounds__(256) void wt_kernel(const float* __restrict__ W,
                                                 short* __restrict__ Wb) {
    int i = (blockIdx.x * 256 + threadIdx.x) * 4;
    float4 v = *(const float4*)(W + i);
    ushort4 o; o.x = f2bf(v.x); o.y = f2bf(v.y); o.z = f2bf(v.z); o.w = f2bf(v.w);
    *(ushort4*)((unsigned short*)Wb + i) = o;
}

// ---------- kernel 2: fused adjacency + diffusion + projection ---------------
// grid = 256 blocks (XCD-swizzled), 512 threads = 8 waves.
// wave w: rg2 = w&1 (n-subtile of 32), mh4 = w>>1 (m/d/j-subtile of 32).
// 32x32x16 MFMA; swapped operands throughout (D row = A-row idx, col = B-row idx).
__global__ __launch_bounds__(512, 2) void attn_kernel(
        const short* __restrict__ xb, const short* __restrict__ xbT,
        const float* __restrict__ x2, const short* __restrict__ Wb,
        const float* __restrict__ log_sigmas, const float* __restrict__ pb,
        float* __restrict__ out) {
    __shared__ char smem[150528] __attribute__((aligned(128)));
    char* Kbuf = smem;                  // 2 x 32768: [128 m][256B], granule^=(row&15)
    char* Vbuf = smem + 65536;          // 2 x 32768: [128 d][256B], granule^=(d&15)
    char* Wsb  = smem + 131072;         // [64 n][272B]
    char* x2s  = smem + 148480;         // 2 x 1024 (first 512B used)

    int tid = threadIdx.x, lane = tid & 63, w = tid >> 6;
    int l5 = lane & 31, hi = lane >> 5;
    int rg2 = w & 1, mh4 = w >> 1;

    // XCD-bijective swizzle: XCD k gets 32 consecutive logical blocks
    int bid = (blockIdx.x & 7) * 32 + (blockIdx.x >> 3);
    int b = bid >> 6, n0 = (bid & 63) * 64;

    const char* xb_b  = (const char*)(xb  + (size_t)b * NN * DD);
    const char* xbT_b = (const char*)(xbT + (size_t)b * NN * DD);
    const float* x2b  = x2 + (size_t)b * NN;

    float invd[4];
    #pragma unroll
    for (int h = 0; h < 4; ++h) {
        float sg = __expf(log_sigmas[h]);
        invd[h] = 1.0f / (2.0f * sg * sg + 1e-6f);
    }
    bool same = (invd[0] == invd[1]) && (invd[1] == invd[2]) && (invd[2] == invd[3]);
    float c0 = -invd[0];

    // Q fragments: rows n0 + rg2*32 + l5, k-chunks of 16
    bf16x8 qf[8];
    {
        const char* qr = xb_b + (size_t)(n0 + rg2 * 32 + l5) * 256 + hi * 16;
        #pragma unroll
        for (int ck = 0; ck < 8; ++ck)
            qf[ck] = *(const bf16x8*)(qr + ck * 32);
    }
    float x2n = x2b[n0 + rg2 * 32 + l5];

    f32x16 O;
    #pragma unroll
    for (int i = 0; i < 16; ++i) O[i] = 0.f;

    auto stage = [&](int bsel, int m1) {
        #pragma unroll
        for (int ii = 0; ii < 4; ++ii) {
            int I = w * 4 + ii;
            int row = I * 4 + (lane >> 4);
            int g = (lane & 15) ^ (row & 15);
            gload16(xb_b + (size_t)(m1 + row) * 256 + g * 16,
                    Kbuf + bsel * 32768 + I * 1024);
        }
        #pragma unroll
        for (int ii = 0; ii < 4; ++ii) {
            int I = w * 4 + ii;
            int d = I * 4 + (lane >> 4);
            int g = (lane & 15) ^ (d & 15);
            gload16(xbT_b + (size_t)d * (NN * 2) + (size_t)m1 * 2 + g * 16,
                    Vbuf + bsel * 32768 + I * 1024);
        }
        if (w == 0)
            gload16((const char*)x2b + m1 * 4 + (lane & 31) * 16, x2s + bsel * 1024);
    };

    stage(0, 0);
    asm volatile("s_waitcnt vmcnt(0)" ::: "memory");
    __builtin_amdgcn_s_barrier();
    __builtin_amdgcn_sched_barrier(0);

    int cur = 0;
    for (int t = 0; t < NN / 128; ++t) {
        if (t < NN / 128 - 1) stage(cur ^ 1, (t + 1) * 128);

        const char* Kc = Kbuf + cur * 32768;
        const char* Vc = Vbuf + cur * 32768;
        const float* xm = (const float*)(x2s + cur * 1024) + mh4 * 32;

        // S = K . Q^T : D[m][n], col = n = l5, row m-off = (reg&3)+8*(reg>>2)+4*hi
        f32x16 S;
        #pragma unroll
        for (int i = 0; i < 16; ++i) S[i] = 0.f;
        {
            int mrow = mh4 * 32 + l5;
            const char* kr = Kc + mrow * 256;
            int sw = mrow & 15;
            #pragma unroll
            for (int ck = 0; ck < 8; ++ck) {
                bf16x8 af = *(const bf16x8*)(kr + (((2 * ck + hi) ^ sw) * 16));
                S = __builtin_amdgcn_mfma_f32_32x32x16_bf16(af, qf[ck], S, 0, 0, 0);
            }
        }
        // weights -> bf16 -> Ws (4 x b64 per lane)
        #pragma unroll
        for (int q = 0; q < 4; ++q) {
            float4 xmq = *(const float4*)(xm + 8 * q + 4 * hi);
            float wv[4];
            #pragma unroll
            for (int r = 0; r < 4; ++r) {
                float x2m = ((const float*)&xmq)[r];
                float dsq = fmaxf(x2n + x2m - 2.0f * S[q * 4 + r], 0.0f);
                if (same) wv[r] = __expf(dsq * c0);
                else wv[r] = 0.25f * (__expf(-dsq * invd[0]) + __expf(-dsq * invd[1]) +
                                      __expf(-dsq * invd[2]) + __expf(-dsq * invd[3]));
            }
            uint2 pk;
            pk.x = (unsigned)f2bf(wv[0]) | ((unsigned)f2bf(wv[1]) << 16);
            pk.y = (unsigned)f2bf(wv[2]) | ((unsigned)f2bf(wv[3]) << 16);
            *(uint2*)(Wsb + (rg2 * 32 + l5) * 272 + (mh4 * 32 + 8 * q + 4 * hi) * 2) = pk;
        }
        // Ws visible; staged vmem stays in flight (T4)
        asm volatile("s_waitcnt lgkmcnt(0)" ::: "memory");
        __builtin_amdgcn_s_barrier();
        __builtin_amdgcn_sched_barrier(0);

        // O[d][n] += V . W^T : a = V[d][m16], b = Ws[n][m16]
        {
            int drow = mh4 * 32 + l5;
            const char* vr = Vc + drow * 256;
            int sw = drow & 15;
            const char* wsr = Wsb + (rg2 * 32 + l5) * 272;
            #pragma unroll
            for (int ck = 0; ck < 8; ++ck) {
                bf16x8 af = *(const bf16x8*)(vr + (((2 * ck + hi) ^ sw) * 16));
                bf16x8 bf = *(const bf16x8*)(wsr + ck * 32 + hi * 16);
                O = __builtin_amdgcn_mfma_f32_32x32x16_bf16(af, bf, O, 0, 0, 0);
            }
        }
        __syncthreads();   // staged buffer ready; all Ws/V reads done
        cur ^= 1;
    }

    // -------- epilogue: projection via MFMA, Wb direct from global --------
    short* Os = (short*)smem;   // [64 n][272B] bf16
    #pragma unroll
    for (int q = 0; q < 4; ++q) {
        uint2 pk;
        pk.x = (unsigned)f2bf(O[q * 4 + 0]) | ((unsigned)f2bf(O[q * 4 + 1]) << 16);
        pk.y = (unsigned)f2bf(O[q * 4 + 2]) | ((unsigned)f2bf(O[q * 4 + 3]) << 16);
        *(uint2*)((char*)Os + (rg2 * 32 + l5) * 272 + (mh4 * 32 + 8 * q + 4 * hi) * 2) = pk;
    }
    __syncthreads();

    // P[n][j] : a = Os[n][d16], b = Wb[j][d16] (global, L2-hot)
    f32x16 P;
    #pragma unroll
    for (int i = 0; i < 16; ++i) P[i] = 0.f;
    {
        const char* osr = (const char*)Os + (rg2 * 32 + l5) * 272;
        const char* wbr = (const char*)Wb + (size_t)(mh4 * 32 + l5) * 256;
        #pragma unroll
        for (int ck = 0; ck < 8; ++ck) {
            bf16x8 af = *(const bf16x8*)(osr + ck * 32 + hi * 16);
            bf16x8 bf = *(const bf16x8*)(wbr + ck * 32 + hi * 16);
            P = __builtin_amdgcn_mfma_f32_32x32x16_bf16(af, bf, P, 0, 0, 0);
        }
    }
    float pbj = pb[mh4 * 32 + l5];
    float* ob = out + ((size_t)b * NN + n0) * DD;
    #pragma unroll
    for (int q = 0; q < 4; ++q)
        #pragma unroll
        for (int r = 0; r < 4; ++r)
            ob[(size_t)(rg2 * 32 + r + 8 * q + 4 * hi) * DD + mh4 * 32 + l5] =
                P[q * 4 + r] + pbj;
}

// ---------- kernel 3: ELU + residual + LayerNorm (in-place, elementwise) -----
__global__ __launch_bounds__(256) void epi_kernel(const float* __restrict__ x,
        const float* __restrict__ gamma, const float* __restrict__ beta,
        float* io) {
    int lane = threadIdx.x & 63, wv = threadIdx.x >> 6;
    float g0 = gamma[lane * 2], g1 = gamma[lane * 2 + 1];
    float b0 = beta[lane * 2], b1 = beta[lane * 2 + 1];
    #pragma unroll
    for (int it = 0; it < 2; ++it) {
        size_t row = (size_t)blockIdx.x * 8 + it * 4 + wv;
        float2 o = *(const float2*)(io + row * DD + lane * 2);
        float2 xv = *(const float2*)(x + row * DD + lane * 2);
        float y0 = (o.x > 0.f ? o.x : __expf(o.x) - 1.f) + xv.x;
        float y1 = (o.y > 0.f ? o.y : __expf(o.y) - 1.f) + xv.y;
        float s = y0 + y1;
        #pragma unroll
        for (int off = 32; off; off >>= 1) s += __shfl_xor(s, off);
        float mu = s * 0.0078125f;
        float d0 = y0 - mu, d1 = y1 - mu;
        float v = d0 * d0 + d1 * d1;
        #pragma unroll
        for (int off = 32; off; off >>= 1) v += __shfl_xor(v, off);
        float inv = rsqrtf(v * 0.0078125f + 1e-5f);
        float2 rr; rr.x = d0 * inv * g0 + b0; rr.y = d1 * inv * g1 + b1;
        *(float2*)(io + row * DD + lane * 2) = rr;
    }
}

extern "C" void kernel_launch(void* const* d_in, const int* in_sizes, int n_in,
                              void* d_out, int out_size, void* d_ws, size_t ws_size,
                              hipStream_t stream) {
    const float* x  = (const float*)d_in[0];
    const float* ls = (const float*)d_in[1];
    const float* pw = (const float*)d_in[2];
    const float* pb = (const float*)d_in[3];
    const float* g  = (const float*)d_in[4];
    const float* be = (const float*)d_in[5];
    float* out = (float*)d_out;

    char* ws = (char*)d_ws;
    short* xb  = (short*)ws;                                  // 4 MB
    short* xbT = (short*)(ws + (size_t)4 * 1024 * 1024);      // 4 MB
    float* x2  = (float*)(ws + (size_t)8 * 1024 * 1024);      // 64 KB
    short* Wb  = (short*)(ws + (size_t)8 * 1024 * 1024 + 65536);  // 32 KB

    prep_kernel<<<dim3(BB * NN / 64), dim3(256), 0, stream>>>(x, xb, xbT, x2);
    wt_kernel<<<dim3(16), dim3(256), 0, stream>>>(pw, Wb);
    attn_kernel<<<dim3(BB * NN / 64), dim3(512), 0, stream>>>(xb, xbT, x2, Wb, ls, pb, out);
    epi_kernel<<<dim3(BB * NN / 8), dim3(256), 0, stream>>>(x, g, be, out);
}

// Round 5
// 50.671 us; speedup vs baseline: 5.9953x; 1.8450x over previous
//
#include <hip/hip_runtime.h>
#include <hip/hip_bf16.h>

#define BB 4
#define NN 4096
#define DD 128

typedef __attribute__((ext_vector_type(8))) short bf16x8;
typedef __attribute__((ext_vector_type(16))) float f32x16;

__device__ __forceinline__ unsigned short f2bf(float f) {
    unsigned int u = __float_as_uint(f);
    return (unsigned short)((u + 0x7FFFu + ((u >> 16) & 1u)) >> 16);
}
__device__ __forceinline__ float bf2f(unsigned short s) {
    return __uint_as_float(((unsigned int)s) << 16);
}

// ---------------------------------------------------------------------------
// Fragment-major layouts (shorts):
//   xbF: row-block rb = n>>5 (global over B*N), granule g = k>>3 (0..15),
//        addr = rb*4096 + g*256 + (n&31)*8 + (k&7)
//   vF:  per batch: d-block db = d>>5 (0..3), m-granule g = m>>3 (0..511),
//        addr = b*524288 + db*131072 + g*256 + (d&31)*8 + (m&7)
//   wbF: j-block jb = j>>5, granule g = k>>3, addr = jb*4096 + g*256 + (j&31)*8
// A- and B-operand fragments are both "lane=row, bf16x8 = k-granule 2ck+hi".
// ---------------------------------------------------------------------------

__global__ __launch_bounds__(256) void prep_kernel(const float* __restrict__ x,
        short* __restrict__ xbF, short* __restrict__ vF, float* __restrict__ x2) {
    __shared__ short Ls[64 * 136];
    int tid = threadIdx.x;
    int r = tid >> 2, cq = tid & 3;
    size_t rowg = (size_t)blockIdx.x * 64 + r;     // global row (over B*N)
    const float* xp = x + rowg * DD + cq * 32;
    short tmp[32];
    float s = 0.f;
    #pragma unroll
    for (int i = 0; i < 8; ++i) {
        float4 v = ((const float4*)xp)[i];
        unsigned short b0 = f2bf(v.x), b1 = f2bf(v.y), b2 = f2bf(v.z), b3 = f2bf(v.w);
        tmp[i*4+0] = (short)b0; tmp[i*4+1] = (short)b1;
        tmp[i*4+2] = (short)b2; tmp[i*4+3] = (short)b3;
        float f0 = bf2f(b0), f1 = bf2f(b1), f2 = bf2f(b2), f3 = bf2f(b3);
        s += f0*f0 + f1*f1 + f2*f2 + f3*f3;
    }
    // frag-major write + LDS stash for transpose
    #pragma unroll
    for (int c = 0; c < 4; ++c) {
        uint4 v = ((uint4*)tmp)[c];
        *(uint4*)(xbF + (rowg >> 5) * 4096 + (size_t)(cq * 4 + c) * 256 + (rowg & 31) * 8) = v;
        *(uint4*)(&Ls[r * 136 + cq * 32 + c * 8]) = v;
    }
    s += __shfl_xor(s, 1); s += __shfl_xor(s, 2);
    if ((tid & 3) == 0) x2[rowg] = s;
    __syncthreads();
    // transposed frag-major write (vF)
    int d = (tid & 63) + ((tid >> 7) << 6);        // 0..127
    int nh = (tid >> 6) & 1;
    short arr[32];
    #pragma unroll
    for (int i = 0; i < 32; ++i) arr[i] = Ls[(nh * 32 + i) * 136 + d];
    int blk = blockIdx.x;
    int b = blk >> 6;
    int mbase = (blk & 63) * 64 + nh * 32;          // m within batch
    size_t base = (size_t)b * 524288 + (size_t)(d >> 5) * 131072 + (size_t)(d & 31) * 8;
    #pragma unroll
    for (int c = 0; c < 4; ++c)
        *(uint4*)(vF + base + (size_t)((mbase >> 3) + c) * 256) = ((uint4*)arr)[c];
}

__global__ __launch_bounds__(256) void wt_kernel(const float* __restrict__ W,
                                                 short* __restrict__ wbF) {
    int t = blockIdx.x * 256 + threadIdx.x;   // 0..4095
    int j = t >> 5, cq = t & 31;              // j row, k-chunk of 4
    float4 v = *(const float4*)(W + j * 128 + cq * 4);
    uint2 pk;
    pk.x = (unsigned)f2bf(v.x) | ((unsigned)f2bf(v.y) << 16);
    pk.y = (unsigned)f2bf(v.z) | ((unsigned)f2bf(v.w) << 16);
    *(uint2*)(wbF + (j >> 5) * 4096 + (cq >> 1) * 256 + (j & 31) * 8 + (cq & 1) * 4) = pk;
}

// ---------------------------------------------------------------------------
// attn: 256 blocks x 512 threads (8 waves). n-tile 64/block, m-tile 256/iter.
// QK: wave w owns m-range w*32 (full n=64). PV: wave w = (d-blk w&3, n-half w>>2).
// K/V/Q/proj-W fragments straight from global (L2); LDS only for Ws + epilogue.
// ---------------------------------------------------------------------------
__global__ __launch_bounds__(512, 2) void attn_kernel(
        const short* __restrict__ xbF, const short* __restrict__ vF,
        const float* __restrict__ x2, const short* __restrict__ wbF,
        const float* __restrict__ log_sigmas, const float* __restrict__ pb,
        const float* __restrict__ x, const float* __restrict__ gamma,
        const float* __restrict__ beta, float* __restrict__ out) {
    __shared__ char smem[50304] __attribute__((aligned(128)));
    short* Ws = (short*)smem;                 // [64 n][512B m], granule ^= (row&31)
    int* flags = (int*)(smem + 50176);        // 2 x 8 ints

    int tid = threadIdx.x, lane = tid & 63, w = tid >> 6;
    int l5 = lane & 31, hi = lane >> 5;

    int bid = (blockIdx.x & 7) * 32 + (blockIdx.x >> 3);   // XCD-bijective
    int b = bid >> 6, n0 = (bid & 63) * 64;

    const short* xf_b = xbF + (size_t)b * 524288;
    const short* vf_b = vF + (size_t)b * 524288;
    const float* x2b = x2 + (size_t)b * NN;

    float invd[4];
    #pragma unroll
    for (int h = 0; h < 4; ++h) {
        float sg = __expf(log_sigmas[h]);
        invd[h] = 1.0f / (2.0f * sg * sg + 1e-6f);
    }
    bool same = (invd[0] == invd[1]) && (invd[1] == invd[2]) && (invd[2] == invd[3]);
    float c0 = -invd[0];
    float invd_min = fminf(fminf(invd[0], invd[1]), fminf(invd[2], invd[3]));
    float thr = 30.0f / invd_min;

    // Q fragments (B-operand): rows n0+l5 (half A), n0+32+l5 (half B)
    bf16x8 qa[8], qb[8];
    {
        const short* qp = xf_b + (n0 >> 5) * 4096;
        #pragma unroll
        for (int ck = 0; ck < 8; ++ck) {
            qa[ck] = *(const bf16x8*)(qp + (2 * ck + hi) * 256 + l5 * 8);
            qb[ck] = *(const bf16x8*)(qp + 4096 + (2 * ck + hi) * 256 + l5 * 8);
        }
    }
    float x2nA = x2b[n0 + l5], x2nB = x2b[n0 + 32 + l5];

    f32x16 O;
    #pragma unroll
    for (int i = 0; i < 16; ++i) O[i] = 0.f;

    int fb = 0;
    for (int t = 0; t < NN / 256; ++t) {
        int m1 = t * 256;
        // K fragments (A-operand): rows m1 + w*32 + l5
        const short* kp = xf_b + (t * 8 + w) * 4096;
        bf16x8 kf[8];
        #pragma unroll
        for (int ck = 0; ck < 8; ++ck)
            kf[ck] = *(const bf16x8*)(kp + (2 * ck + hi) * 256 + l5 * 8);
        f32x16 SA, SB;
        #pragma unroll
        for (int i = 0; i < 16; ++i) { SA[i] = 0.f; SB[i] = 0.f; }
        #pragma unroll
        for (int ck = 0; ck < 8; ++ck) {
            SA = __builtin_amdgcn_mfma_f32_32x32x16_bf16(kf[ck], qa[ck], SA, 0, 0, 0);
            SB = __builtin_amdgcn_mfma_f32_32x32x16_bf16(kf[ck], qb[ck], SB, 0, 0, 0);
        }
        // dist^2: row m = m1+w*32+(8q+4hi+r), col n (A: n0+l5, B: n0+32+l5)
        float4 xm[4];
        #pragma unroll
        for (int q = 0; q < 4; ++q)
            xm[q] = *(const float4*)(x2b + m1 + w * 32 + 8 * q + 4 * hi);
        float dv[32];
        #pragma unroll
        for (int q = 0; q < 4; ++q)
            #pragma unroll
            for (int r = 0; r < 4; ++r) {
                float m2 = ((const float*)&xm[q])[r];
                dv[q * 4 + r]      = x2nA + m2 - 2.0f * SA[q * 4 + r];
                dv[16 + q * 4 + r] = x2nB + m2 - 2.0f * SB[q * 4 + r];
            }
        float pmin = dv[0];
        #pragma unroll
        for (int i = 1; i < 32; ++i) pmin = fminf(pmin, dv[i]);
        bool skipw = __all(pmin > thr);

        // Ws rows l5 (half A) and 32+l5 (half B); swizzle granule ^= l5
        if (skipw) {
            uint2 z; z.x = 0; z.y = 0;
            #pragma unroll
            for (int q = 0; q < 4; ++q) {
                *(uint2*)((char*)Ws + l5 * 512 + ((4 * w + q) ^ l5) * 16 + 8 * hi) = z;
                *(uint2*)((char*)Ws + (32 + l5) * 512 + ((4 * w + q) ^ l5) * 16 + 8 * hi) = z;
            }
        } else {
            #pragma unroll
            for (int h2 = 0; h2 < 2; ++h2) {
                int rowb = h2 * 32 + l5;
                #pragma unroll
                for (int q = 0; q < 4; ++q) {
                    float wv[4];
                    #pragma unroll
                    for (int r = 0; r < 4; ++r) {
                        float c = fmaxf(dv[h2 * 16 + q * 4 + r], 0.0f);
                        if (same) wv[r] = __expf(c * c0);
                        else wv[r] = 0.25f * (__expf(-c * invd[0]) + __expf(-c * invd[1]) +
                                              __expf(-c * invd[2]) + __expf(-c * invd[3]));
                    }
                    uint2 pk;
                    pk.x = (unsigned)f2bf(wv[0]) | ((unsigned)f2bf(wv[1]) << 16);
                    pk.y = (unsigned)f2bf(wv[2]) | ((unsigned)f2bf(wv[3]) << 16);
                    *(uint2*)((char*)Ws + rowb * 512 + ((4 * w + q) ^ l5) * 16 + 8 * hi) = pk;
                }
            }
        }
        if (lane == 0) flags[fb * 8 + w] = skipw ? 1 : 0;
        __syncthreads();
        const int4* fp = (const int4*)(flags + fb * 8);
        int4 f0 = fp[0], f1 = fp[1];
        bool allskip = (f0.x & f0.y & f0.z & f0.w & f1.x & f1.y & f1.z & f1.w) != 0;
        fb ^= 1;
        if (!allskip) {
            int db = w & 3, nh = w >> 2;
            const short* vp = vf_b + db * 131072 + (m1 >> 3) * 256;
            const char* wsr = (const char*)Ws + (nh * 32 + l5) * 512;
            #pragma unroll
            for (int ck = 0; ck < 16; ++ck) {
                bf16x8 af = *(const bf16x8*)(vp + (2 * ck + hi) * 256 + l5 * 8);
                bf16x8 bf = *(const bf16x8*)(wsr + (((2 * ck + hi) ^ l5) * 16));
                O = __builtin_amdgcn_mfma_f32_32x32x16_bf16(af, bf, O, 0, 0, 0);
            }
            __syncthreads();
        }
    }

    // ---- epilogue: O -> Obf(LDS) -> proj MFMA -> P(LDS) -> ELU+res+LN -> out
    short* Obf = (short*)smem;                 // [64 n][256B d], granule ^= (row&15)
    {
        int db = w & 3, nh = w >> 2;
        int orow = nh * 32 + l5;
        #pragma unroll
        for (int q = 0; q < 4; ++q) {
            uint2 pk;
            pk.x = (unsigned)f2bf(O[q * 4 + 0]) | ((unsigned)f2bf(O[q * 4 + 1]) << 16);
            pk.y = (unsigned)f2bf(O[q * 4 + 2]) | ((unsigned)f2bf(O[q * 4 + 3]) << 16);
            *(uint2*)((char*)Obf + orow * 256 + ((4 * db + q) ^ (l5 & 15)) * 16 + 8 * hi) = pk;
        }
    }
    __syncthreads();

    float* Plds = (float*)(smem + 16384);      // [64 n][132 f32]
    {
        int jq = w & 3, nh2 = w >> 2;
        f32x16 P;
        #pragma unroll
        for (int i = 0; i < 16; ++i) P[i] = 0.f;
        const short* wp = wbF + jq * 4096;
        const char* obr = (const char*)Obf + (nh2 * 32 + l5) * 256;
        #pragma unroll
        for (int ck = 0; ck < 8; ++ck) {
            bf16x8 af = *(const bf16x8*)(obr + ((2 * ck + hi) ^ (l5 & 15)) * 16);
            bf16x8 bf = *(const bf16x8*)(wp + (2 * ck + hi) * 256 + l5 * 8);
            P = __builtin_amdgcn_mfma_f32_32x32x16_bf16(af, bf, P, 0, 0, 0);
        }
        float pbj = pb[jq * 32 + l5];
        #pragma unroll
        for (int q = 0; q < 4; ++q)
            #pragma unroll
            for (int r = 0; r < 4; ++r) {
                int prow = nh2 * 32 + 8 * q + 4 * hi + r;
                Plds[prow * 132 + jq * 32 + l5] = P[q * 4 + r] + pbj;
            }
    }
    __syncthreads();

    {
        int row = tid >> 3, part = tid & 7;
        const float* xr = x + ((size_t)b * NN + n0 + row) * DD + part * 16;
        float y[16];
        float sum = 0.f, ss = 0.f;
        #pragma unroll
        for (int c = 0; c < 4; ++c) {
            float4 pv = *(const float4*)(Plds + row * 132 + part * 16 + c * 4);
            float4 xv = *(const float4*)(xr + c * 4);
            #pragma unroll
            for (int k = 0; k < 4; ++k) {
                float p = ((const float*)&pv)[k];
                float e = (p > 0.f ? p : __expf(p) - 1.f) + ((const float*)&xv)[k];
                y[c * 4 + k] = e;
                sum += e; ss += e * e;
            }
        }
        sum += __shfl_xor(sum, 1); ss += __shfl_xor(ss, 1);
        sum += __shfl_xor(sum, 2); ss += __shfl_xor(ss, 2);
        sum += __shfl_xor(sum, 4); ss += __shfl_xor(ss, 4);
        float mu = sum * 0.0078125f;
        float var = fmaxf(ss * 0.0078125f - mu * mu, 0.f);
        float inv = rsqrtf(var + 1e-5f);
        float* op = out + ((size_t)b * NN + n0 + row) * DD + part * 16;
        #pragma unroll
        for (int c = 0; c < 4; ++c) {
            float4 gv = *(const float4*)(gamma + part * 16 + c * 4);
            float4 bv = *(const float4*)(beta + part * 16 + c * 4);
            float4 o;
            ((float*)&o)[0] = (y[c*4+0] - mu) * inv * ((const float*)&gv)[0] + ((const float*)&bv)[0];
            ((float*)&o)[1] = (y[c*4+1] - mu) * inv * ((const float*)&gv)[1] + ((const float*)&bv)[1];
            ((float*)&o)[2] = (y[c*4+2] - mu) * inv * ((const float*)&gv)[2] + ((const float*)&bv)[2];
            ((float*)&o)[3] = (y[c*4+3] - mu) * inv * ((const float*)&gv)[3] + ((const float*)&bv)[3];
            *(float4*)(op + c * 4) = o;
        }
    }
}

extern "C" void kernel_launch(void* const* d_in, const int* in_sizes, int n_in,
                              void* d_out, int out_size, void* d_ws, size_t ws_size,
                              hipStream_t stream) {
    const float* x  = (const float*)d_in[0];
    const float* ls = (const float*)d_in[1];
    const float* pw = (const float*)d_in[2];
    const float* pb = (const float*)d_in[3];
    const float* g  = (const float*)d_in[4];
    const float* be = (const float*)d_in[5];
    float* out = (float*)d_out;

    char* ws = (char*)d_ws;
    short* xbF = (short*)ws;                                       // 4 MB
    short* vF  = (short*)(ws + (size_t)4 * 1024 * 1024);           // 4 MB
    float* x2  = (float*)(ws + (size_t)8 * 1024 * 1024);           // 64 KB
    short* wbF = (short*)(ws + (size_t)8 * 1024 * 1024 + 65536);   // 32 KB

    prep_kernel<<<dim3(BB * NN / 64), dim3(256), 0, stream>>>(x, xbF, vF, x2);
    wt_kernel<<<dim3(16), dim3(256), 0, stream>>>(pw, wbF);
    attn_kernel<<<dim3(BB * NN / 64), dim3(512), 0, stream>>>(
        xbF, vF, x2, wbF, ls, pb, x, g, be, out);
}